// Round 11
// baseline (205.039 us; speedup 1.0000x reference)
//
#include <hip/hip_runtime.h>

// PointMLP stage: KNN(24) -> groupnorm+concat -> 2x res_block (D=128) -> max over K
//                 -> 2x res_block -> gather by fps_idx.
// fp16 MFMA (16x16x32).
// k_pre v6 (t-split + slim LN): R10 structure (block = 4 points, wave-pair shares a
//   48-row slab, each wave computes 4 of 8 output tiles, 96->~115 VGPR fits the
//   128-cap of (256,2)) with the VALU-slim epilogue:
//   - su via 9th rowsum MFMA tile (K spans all 128 ch, so full-row sum in-register;
//     no su accumulate, no su DPP, sq-only cross-wave exchange)
//   - normalize as single fma: y = x*c1 + c0, c1 = rstd*gamma, c0 = beta - mean*c1.
// Perf law (R6-R10): k_pre was VALU-issue-bound in the LN epilogue (VALUBusy 58%,
//   MfmaUtil 14%); this cuts epilogue VALU ~2.2x at +4 MFMA/GEMM.
// k_pos keeps the 9-tile rowsum-LN path (W matrices 4..7 of wp).
// KNN: u64 keys, threshold+compact+bitonic (R5 design).
// ws: wp[0,294912) fp16 weights (9 tiles/matrix); idx[512K,2M); h0[2M,6M) f16; h1[6M,14M) f32.

typedef _Float16 half8  __attribute__((ext_vector_type(8)));
typedef _Float16 half4v __attribute__((ext_vector_type(4)));
typedef _Float16 h2v    __attribute__((ext_vector_type(2)));
typedef float    f32x4  __attribute__((ext_vector_type(4)));
typedef unsigned long long u64;

#define DEVINL __device__ __forceinline__

union H8 { half8 v; h2v p[4]; int w[4]; };
union H4 { half4v v; h2v p[2]; };

DEVINL f32x4 splat4(float s) { f32x4 r = {s, s, s, s}; return r; }

DEVINL _Float16 hmax1(_Float16 a, _Float16 b) { return a > b ? a : b; }
DEVINL h2v hmax2v(h2v a, h2v b) {
  h2v r; r[0] = hmax1(a[0], b[0]); r[1] = hmax1(a[1], b[1]); return r;
}
DEVINL h2v cvt2h(float lo, float hi) {
  return __builtin_bit_cast(h2v, __builtin_amdgcn_cvt_pkrtz(lo, hi));
}
DEVINL half8 hmax8(half8 a, half8 b) {
  H8 A, B, R; A.v = a; B.v = b;
  #pragma unroll
  for (int e = 0; e < 4; ++e) R.p[e] = hmax2v(A.p[e], B.p[e]);
  return R.v;
}

// 16-lane (DPP row) all-reduce add.
DEVINL float dpp_add16(float x) {
  int v = __builtin_bit_cast(int, x);
  x += __builtin_bit_cast(float, __builtin_amdgcn_update_dpp(v, v, 0xB1, 0xF, 0xF, true));
  v = __builtin_bit_cast(int, x);
  x += __builtin_bit_cast(float, __builtin_amdgcn_update_dpp(v, v, 0x4E, 0xF, 0xF, true));
  v = __builtin_bit_cast(int, x);
  x += __builtin_bit_cast(float, __builtin_amdgcn_update_dpp(v, v, 0x141, 0xF, 0xF, true));
  v = __builtin_bit_cast(int, x);
  x += __builtin_bit_cast(float, __builtin_amdgcn_update_dpp(v, v, 0x140, 0xF, 0xF, true));
  return x;
}

// ---- swizzled LDS helpers: row stride 256B, XOR 16B-chunk swizzle with (row&7) ----
DEVINL void stH(_Float16* L, int row, int col, _Float16 v) {
  const int b2 = col * 2;
  *(_Float16*)((char*)L + row * 256 + (((b2 >> 4) ^ (row & 7)) << 4) + (b2 & 15)) = v;
}
DEVINL half8 ldA(const _Float16* L, int row, int ch) {
  return *(const half8*)((const char*)L + row * 256 + ((ch ^ (row & 7)) << 4));
}
DEVINL void stA(_Float16* L, int row, int ch, half8 v) {
  *(half8*)((char*)L + row * 256 + ((ch ^ (row & 7)) << 4)) = v;
}
DEVINL void stA4(_Float16* L, int row, int ch, int hf, half4v v) {
  *(half4v*)((char*)L + row * 256 + ((ch ^ (row & 7)) << 4) + hf * 8) = v;
}
DEVINL half4v ldA4(const _Float16* L, int row, int ch, int hf) {
  return *(const half4v*)((const char*)L + row * 256 + ((ch ^ (row & 7)) << 4) + hf * 8);
}

// ---- k_pre GEMM: A(LDS slab, 48 rows) @ {4 own tiles + rowsum tile 8} ----
DEVINL void mm45(const _Float16* L, const _Float16* __restrict__ W, int hf,
                 f32x4 acc[3][4], f32x4 accsu[3], int lane) {
  const int g = lane >> 4, r = lane & 15;
  #pragma unroll
  for (int s = 0; s < 4; ++s) {
    half8 bfr[4];
    #pragma unroll
    for (int t = 0; t < 4; ++t)
      bfr[t] = *(const half8*)(W + (((s * 9 + hf * 4 + t) * 64 + lane) * 8));
    const half8 bsu = *(const half8*)(W + (((s * 9 + 8) * 64 + lane) * 8));
    #pragma unroll
    for (int mt = 0; mt < 3; ++mt) {
      const half8 a = ldA(L, mt * 16 + r, s * 4 + g);
      #pragma unroll
      for (int t = 0; t < 4; ++t)
        acc[mt][t] = __builtin_amdgcn_mfma_f32_16x16x32_f16(a, bfr[t], acc[mt][t], 0, 0, 0);
      accsu[mt] = __builtin_amdgcn_mfma_f32_16x16x32_f16(a, bsu, accsu[mt], 0, 0, 0);
    }
  }
}

// ---- k_pre LN (slim): su from rowsum tile; sq partial via DPP + cross-wave LDS
// exchange (sq only); normalize = 1 fma. Contains one __syncthreads. ----
DEVINL void epi_ln_pair(f32x4 acc[3][4], f32x4 accsu[3],
                        const float* __restrict__ bv, const float* __restrict__ gv,
                        const float* __restrict__ bbv, int lane, int wid, float (*SQ)[48]) {
  const int g = lane >> 4, cr = lane & 15, hf = wid & 1;
  const f32x4 bo = *(const f32x4*)(bv + cr * 8 + hf * 4);
  const f32x4 bq = *(const f32x4*)(bv + cr * 8 + (hf ^ 1) * 4);
  const f32x4 gp = *(const f32x4*)(gv + cr * 8 + hf * 4);
  const f32x4 ap = *(const f32x4*)(bbv + cr * 8 + hf * 4);
  const f32x4 bs4 = bo + bq;
  const float sb = dpp_add16(bs4[0] + bs4[1] + bs4[2] + bs4[3]);
  f32x4 sqs[3];
  #pragma unroll
  for (int mt = 0; mt < 3; ++mt) {
    f32x4 sq4 = splat4(0.f);
    #pragma unroll
    for (int t = 0; t < 4; ++t) {
      const f32x4 x = acc[mt][t] + splat4(bo[t]);
      acc[mt][t] = x;
      sq4 = sq4 + x * x;
    }
    #pragma unroll
    for (int q = 0; q < 4; ++q) sq4[q] = dpp_add16(sq4[q]);
    sqs[mt] = sq4;
  }
  if (cr == 0) {
    #pragma unroll
    for (int mt = 0; mt < 3; ++mt)
      #pragma unroll
      for (int q = 0; q < 4; ++q)
        SQ[wid][mt * 16 + 4 * g + q] = sqs[mt][q];
  }
  __syncthreads();
  #pragma unroll
  for (int mt = 0; mt < 3; ++mt)
    #pragma unroll
    for (int q = 0; q < 4; ++q) {
      const float tsq = sqs[mt][q] + SQ[wid ^ 1][mt * 16 + 4 * g + q];
      const float mean = (accsu[mt][q] + sb) * (1.f / 128.f);
      const float var = fmaxf(tsq * (1.f / 128.f) - mean * mean, 0.f);
      const float rstd = rsqrtf(var + 1e-5f);
      #pragma unroll
      for (int t = 0; t < 4; ++t) {
        const float c1 = rstd * gp[t];
        const float c0 = ap[t] - mean * c1;
        acc[mt][t][q] = fmaf(acc[mt][t][q], c1, c0);
      }
    }
}

// ---- k_pre res_block on a wave-pair slab; stores output rows back to LDS ----
DEVINL void res_block_pair(_Float16* L, const _Float16* __restrict__ W1, const _Float16* __restrict__ W2,
                           const float* b1, const float* g1, const float* bb1,
                           const float* b2, const float* g2, const float* bb2,
                           half4v xres[3][4], int lane, int wid, float (*SQ)[48]) {
  const int g = lane >> 4, cr = lane & 15, hf = wid & 1;
  const h2v zero2 = {(_Float16)0, (_Float16)0};
  f32x4 acc[3][4], accsu[3];
  #pragma unroll
  for (int mt = 0; mt < 3; ++mt) {
    accsu[mt] = splat4(0.f);
    #pragma unroll
    for (int t = 0; t < 4; ++t) acc[mt][t] = splat4(0.f);
  }
  mm45(L, W1, hf, acc, accsu, lane);
  epi_ln_pair(acc, accsu, b1, g1, bb1, lane, wid, SQ);
  #pragma unroll
  for (int mt = 0; mt < 3; ++mt)
    #pragma unroll
    for (int q = 0; q < 4; ++q) {
      H4 hv;
      hv.p[0] = hmax2v(cvt2h(acc[mt][0][q], acc[mt][1][q]), zero2);
      hv.p[1] = hmax2v(cvt2h(acc[mt][2][q], acc[mt][3][q]), zero2);
      stA4(L, mt * 16 + 4 * g + q, cr, hf, hv.v);
    }
  #pragma unroll
  for (int mt = 0; mt < 3; ++mt) {
    accsu[mt] = splat4(0.f);
    #pragma unroll
    for (int t = 0; t < 4; ++t) acc[mt][t] = splat4(0.f);
  }
  __syncthreads();                         // h rows complete (both halves)
  mm45(L, W2, hf, acc, accsu, lane);
  epi_ln_pair(acc, accsu, b2, g2, bb2, lane, wid, SQ);
  #pragma unroll
  for (int mt = 0; mt < 3; ++mt)
    #pragma unroll
    for (int q = 0; q < 4; ++q) {
      H4 s;
      s.p[0] = cvt2h(acc[mt][0][q], acc[mt][1][q]);
      s.p[1] = cvt2h(acc[mt][2][q], acc[mt][3][q]);
      H4 z; z.v = s.v + xres[mt][q];
      z.p[0] = hmax2v(z.p[0], zero2);
      z.p[1] = hmax2v(z.p[1], zero2);
      xres[mt][q] = z.v;
      stA4(L, mt * 16 + 4 * g + q, cr, hf, z.v);
    }
  __syncthreads();                         // output rows complete
}

// ---- A(LDS) @ B(global, 9-tile incl rowsum): for k_pos ----
template<int MT>
DEVINL void mm_dev(const _Float16* L, const _Float16* __restrict__ W, f32x4 acc[MT][9], int lane) {
  const int g = lane >> 4, r = lane & 15;
  #pragma unroll
  for (int s = 0; s < 4; ++s) {
    half8 bfr[9];
    #pragma unroll
    for (int t = 0; t < 9; ++t)
      bfr[t] = *(const half8*)(W + (((s * 9 + t) * 64 + lane) * 8));
    #pragma unroll
    for (int mt = 0; mt < MT; ++mt) {
      const half8 a = ldA(L, mt * 16 + r, s * 4 + g);
      #pragma unroll
      for (int t = 0; t < 9; ++t)
        acc[mt][t] = __builtin_amdgcn_mfma_f32_16x16x32_f16(a, bfr[t], acc[mt][t], 0, 0, 0);
    }
  }
}

// ---- bias + LN with rowsum tile (k_pos) ----
template<int MT>
DEVINL void epi_ln(f32x4 acc[MT][9], const float* __restrict__ bv, const float* __restrict__ gv,
                   const float* __restrict__ bbv, int lane) {
  const int cr = lane & 15;
  const f32x4 bp0 = *(const f32x4*)(bv + cr * 8),  bp1 = *(const f32x4*)(bv + cr * 8 + 4);
  const f32x4 gp0 = *(const f32x4*)(gv + cr * 8),  gp1 = *(const f32x4*)(gv + cr * 8 + 4);
  const f32x4 ap0 = *(const f32x4*)(bbv + cr * 8), ap1 = *(const f32x4*)(bbv + cr * 8 + 4);
  const f32x4 bs4 = bp0 + bp1;
  const float sb = dpp_add16(bs4[0] + bs4[1] + bs4[2] + bs4[3]);
  #pragma unroll
  for (int mt = 0; mt < MT; ++mt) {
    f32x4 sq4 = splat4(0.f);
    #pragma unroll
    for (int t = 0; t < 8; ++t) {
      const float bias = (t < 4) ? bp0[t & 3] : bp1[t & 3];
      acc[mt][t] = acc[mt][t] + splat4(bias);
      sq4 = sq4 + acc[mt][t] * acc[mt][t];
    }
    #pragma unroll
    for (int q = 0; q < 4; ++q) sq4[q] = dpp_add16(sq4[q]);
    const f32x4 mean = (acc[mt][8] + splat4(sb)) * splat4(1.f / 128.f);
    f32x4 rstd;
    #pragma unroll
    for (int q = 0; q < 4; ++q) {
      const float var = fmaxf(sq4[q] * (1.f / 128.f) - mean[q] * mean[q], 0.f);
      rstd[q] = rsqrtf(var + 1e-5f);
    }
    #pragma unroll
    for (int t = 0; t < 8; ++t) {
      const float gs = (t < 4) ? gp0[t & 3] : gp1[t & 3];
      const float as = (t < 4) ? ap0[t & 3] : ap1[t & 3];
      const f32x4 c1 = rstd * splat4(gs);
      const f32x4 c0 = splat4(as) - mean * c1;
      acc[mt][t] = acc[mt][t] * c1 + c0;
    }
  }
}

// ---- k_pos res_block (global W, 9 tiles). MODE 0: store rows to LDS; 2: f32 to gdst. ----
template<int MT, int MODE>
DEVINL void res_block_dev(_Float16* L, const _Float16* __restrict__ W1, const _Float16* __restrict__ W2,
                          const float* b1, const float* g1, const float* bb1,
                          const float* b2, const float* g2, const float* bb2,
                          half8 xres[MT][4], int lane, float* __restrict__ gdst) {
  const int g = lane >> 4, cr = lane & 15;
  const h2v zero2 = {(_Float16)0, (_Float16)0};
  f32x4 acc[MT][9];
  #pragma unroll
  for (int mt = 0; mt < MT; ++mt)
    #pragma unroll
    for (int t = 0; t < 9; ++t) acc[mt][t] = splat4(0.f);
  mm_dev<MT>(L, W1, acc, lane);
  epi_ln<MT>(acc, b1, g1, bb1, lane);
  __threadfence_block();
  #pragma unroll
  for (int mt = 0; mt < MT; ++mt)
    #pragma unroll
    for (int q = 0; q < 4; ++q) {
      H8 hv;
      #pragma unroll
      for (int e = 0; e < 4; ++e)
        hv.p[e] = hmax2v(cvt2h(acc[mt][2 * e][q], acc[mt][2 * e + 1][q]), zero2);
      stA(L, mt * 16 + 4 * g + q, cr, hv.v);
    }
  #pragma unroll
  for (int mt = 0; mt < MT; ++mt)
    #pragma unroll
    for (int t = 0; t < 9; ++t) acc[mt][t] = splat4(0.f);
  __threadfence_block();
  mm_dev<MT>(L, W2, acc, lane);
  epi_ln<MT>(acc, b2, g2, bb2, lane);
  if constexpr (MODE == 0) __threadfence_block();
  #pragma unroll
  for (int mt = 0; mt < MT; ++mt)
    #pragma unroll
    for (int q = 0; q < 4; ++q) {
      const int row = mt * 16 + 4 * g + q;
      if constexpr (MODE == 2) {
        f32x4 lo, hi;
        #pragma unroll
        for (int e = 0; e < 4; ++e) {
          lo[e] = fmaxf(acc[mt][e][q]     + (float)xres[mt][q][e],     0.f);
          hi[e] = fmaxf(acc[mt][e + 4][q] + (float)xres[mt][q][e + 4], 0.f);
        }
        *(f32x4*)(gdst + row * 128 + cr * 8)     = lo;
        *(f32x4*)(gdst + row * 128 + cr * 8 + 4) = hi;
      } else {
        H8 s;
        #pragma unroll
        for (int e = 0; e < 4; ++e)
          s.p[e] = cvt2h(acc[mt][2 * e][q], acc[mt][2 * e + 1][q]);
        H8 z; z.v = s.v + xres[mt][q];
        #pragma unroll
        for (int e = 0; e < 4; ++e) z.p[e] = hmax2v(z.p[e], zero2);
        xres[mt][q] = z.v;
        if constexpr (MODE == 0) stA(L, row, cr, z.v);
      }
    }
  if constexpr (MODE == 0) __threadfence_block();
}

// ---- K0: pack 8 weight matrices into 9-tile fp16 B-fragment order (tile 8 = rowsum bcast) ----
__global__ __launch_bounds__(256) void k_pack(const float* __restrict__ preW1, const float* __restrict__ preW2,
                                              const float* __restrict__ posW1, const float* __restrict__ posW2,
                                              _Float16* __restrict__ wp) {
  const int o = blockIdx.x * 256 + threadIdx.x;   // 147456 total (576 blocks)
  const int mat = o / 18432, rem = o % 18432;
  const int frag = rem >> 9, li = (rem >> 3) & 63, j = rem & 7;
  const int s = frag / 9, t = frag % 9;
  const int k = s * 32 + ((li >> 4) << 3) + j;
  const int blk = (mat >> 1) & 1, which = mat & 1;
  const float* base = (mat < 4) ? (which ? preW2 : preW1) : (which ? posW2 : posW1);
  const float* Wm = base + blk * 16384;
  float val;
  if (t < 8) {
    val = Wm[k * 128 + (li & 15) * 8 + t];
  } else {
    float ssum = 0.f;
    for (int n = 0; n < 128; ++n) ssum += Wm[k * 128 + n];
    val = ssum;
  }
  wp[o] = (_Float16)val;
}

// ---- KNN helpers ----
DEVINL u64 kmin(u64 a, u64 b) { return a < b ? a : b; }
DEVINL u64 kmax(u64 a, u64 b) { return a > b ? a : b; }
DEVINL u64 min8(const u64* k) {
  u64 a = kmin(k[0], k[1]), b = kmin(k[2], k[3]);
  u64 c = kmin(k[4], k[5]), d = kmin(k[6], k[7]);
  return kmin(kmin(a, b), kmin(c, d));
}
DEVINL void inv8(u64* k, int j) {
  #pragma unroll
  for (int s = 0; s < 8; ++s) k[s] = (s == j) ? ~0ULL : k[s];
}
DEVINL u64 bitonic64(u64 v, int lane) {
  #pragma unroll
  for (int k = 2; k <= 64; k <<= 1) {
    #pragma unroll
    for (int j = k >> 1; j > 0; j >>= 1) {
      const u64 o = __shfl_xor(v, j);
      const bool up = ((lane & k) == 0);
      const bool lower = ((lane & j) == 0);
      v = (lower == up) ? kmin(v, o) : kmax(v, o);
    }
  }
  return v;
}

// ---- K1: exact 24-NN per point, tie-break = smaller index (u64 lex order) ----
__global__ __launch_bounds__(256) void k_knn(const float* __restrict__ xyz, int* __restrict__ idxout) {
  __shared__ float sx[2048], sy[2048], sz[2048];
  __shared__ u64 scand[4][64];
  const int b = blockIdx.x >> 9;
  const int qbase = (blockIdx.x & 511) * 4;
  const float* xb = xyz + (size_t)b * 2048 * 3;
  for (int i = threadIdx.x; i < 2048; i += 256) {
    sx[i] = xb[i * 3 + 0]; sy[i] = xb[i * 3 + 1]; sz[i] = xb[i * 3 + 2];
  }
  __syncthreads();
  const int wid = threadIdx.x >> 6, lane = threadIdx.x & 63;
  const int q = qbase + wid;
  const float qx = sx[q], qy = sy[q], qz = sz[q];
  const float q2 = qx * qx + qy * qy + qz * qz;
  u64 key[32];
  u64 lmin = ~0ULL;
  #pragma unroll
  for (int j = 0; j < 32; ++j) {
    const int m = j * 64 + lane;
    const float mx = sx[m], my = sy[m], mz = sz[m];
    const float m2 = mx * mx + my * my + mz * mz;
    const float d = fmaxf(q2 + m2 - 2.f * (qx * mx + qy * my + qz * mz), 0.f);
    key[j] = ((u64)__builtin_bit_cast(unsigned, d) << 32) | (unsigned)m;
    lmin = kmin(lmin, key[j]);
  }
  const u64 t = __shfl(bitonic64(lmin, lane), 23);
  int c = 0;
  #pragma unroll
  for (int j = 0; j < 32; ++j) c += (key[j] <= t) ? 1 : 0;
  int inc = c;
  #pragma unroll
  for (int off = 1; off < 64; off <<= 1) {
    const int n = __shfl_up(inc, off);
    if (lane >= off) inc += n;
  }
  const int T = __shfl(inc, 63);
  if (T <= 64) {
    int idx = inc - c;
    #pragma unroll
    for (int j = 0; j < 32; ++j)
      if (key[j] <= t) { scand[wid][idx] = key[j]; ++idx; }
    __threadfence_block();
    u64 cand = (lane < T) ? scand[wid][lane] : ~0ULL;
    cand = bitonic64(cand, lane);
    if (lane < 24) idxout[(size_t)(b * 2048 + q) * 24 + lane] = (int)(unsigned)cand;
  } else {
    u64 gk[4];
    #pragma unroll
    for (int g4 = 0; g4 < 4; ++g4) gk[g4] = min8(key + g4 * 8);
    int keep = 0;
    #pragma unroll 1
    for (int r = 0; r < 24; ++r) {
      u64 kk = kmin(kmin(gk[0], gk[1]), kmin(gk[2], gk[3]));
      #pragma unroll
      for (int off = 32; off >= 1; off >>= 1) kk = kmin(__shfl_xor(kk, off), kk);
      const unsigned wm = (unsigned)kk;
      if (lane == r) keep = (int)wm;
      if (lane == (int)(wm & 63)) {
        const int j = (int)(wm >> 6);
        if (j < 16) {
          if (j < 8) { inv8(key,      j);      gk[0] = min8(key);      }
          else       { inv8(key + 8,  j - 8);  gk[1] = min8(key + 8);  }
        } else {
          if (j < 24){ inv8(key + 16, j - 16); gk[2] = min8(key + 16); }
          else       { inv8(key + 24, j - 24); gk[3] = min8(key + 24); }
        }
      }
    }
    if (lane < 24) idxout[(size_t)(b * 2048 + q) * 24 + lane] = keep;
  }
}

// ---- K3: block = 4 points (96 rows). build -> 2 res_blocks (wave-pair t-split) -> K-max ----
__global__ __launch_bounds__(256, 2) void k_pre(
    const float* __restrict__ features, const int* __restrict__ idxin,
    const _Float16* __restrict__ wp, const float* __restrict__ alpha, const float* __restrict__ beta,
    const float* __restrict__ b1, const float* __restrict__ g1, const float* __restrict__ bb1,
    const float* __restrict__ b2, const float* __restrict__ g2, const float* __restrict__ bb2,
    _Float16* __restrict__ h0) {
  __shared__ _Float16 A[96 * 128];         // 24.5KB, swizzled rows 0..95
  __shared__ float SQ[4][48];              // LN sq-partial exchange (768B)
  const int tid = threadIdx.x;
  const int wid = tid >> 6, lane = tid & 63;
  const int pbase = blockIdx.x * 4;        // 4096 blocks x 4 points = 16384, exact
  // build phase: one (pt, ch) pair per thread
  {
    const int pt = tid >> 6, c = tid & 63;
    const int p = pbase + pt;
    const int b = p >> 11, n = p & 2047;
    const float* fb = features + (size_t)b * 2048 * 64;
    const int* ip = idxin + (size_t)p * 24;
    const float al = alpha[c], be = beta[c];
    const float center = fb[n * 64 + c];
    float v[24]; float su = 0.f, sq = 0.f;
    #pragma unroll
    for (int k = 0; k < 24; ++k) {
      v[k] = fb[ip[k] * 64 + c];
      su += v[k]; sq = fmaf(v[k], v[k], sq);
    }
    const float mean = su * (1.f / 24.f);
    const float var = fmaxf((sq - 24.f * mean * mean) * (1.f / 23.f), 0.f);
    const float rs = 1.f / fmaxf(sqrtf(var), 1e-6f);
    const float c1 = rs * al;
    const float c0 = be - mean * c1 - center;
    const _Float16 ch = (_Float16)center;
    const int row0 = pt * 24;
    #pragma unroll
    for (int k = 0; k < 24; ++k) {
      stH(A, row0 + k, c, ch);
      stH(A, row0 + k, 64 + c, (_Float16)fmaf(v[k], c1, c0));
    }
  }
  __syncthreads();
  // GEMM phase: wave-pair (wid>>1) owns a 48-row slab; this wave computes half hf=wid&1
  _Float16* L = A + (wid >> 1) * 48 * 128;
  const int g = lane >> 4, cr = lane & 15, hf = wid & 1;
  half4v xres[3][4];
  #pragma unroll
  for (int mt = 0; mt < 3; ++mt)
    #pragma unroll
    for (int q = 0; q < 4; ++q)
      xres[mt][q] = ldA4(L, mt * 16 + 4 * g + q, cr, hf);
  res_block_pair(L, wp,         wp + 18432,
                 b1,       g1,       bb1,       b2,       g2,       bb2,       xres, lane, wid, SQ);
  res_block_pair(L, wp + 36864, wp + 55296,
                 b1 + 128, g1 + 128, bb1 + 128, b2 + 128, g2 + 128, bb2 + 128, xres, lane, wid, SQ);
  // cooperative K-max: 64 threads, one (point, 8-channel chunk) each
  if (tid < 64) {
    const int pt = tid >> 4, chk = tid & 15;
    const int row0 = pt * 24;
    half8 m = ldA(A, row0, chk);
    #pragma unroll
    for (int k = 1; k < 24; ++k) m = hmax8(m, ldA(A, row0 + k, chk));
    *(half8*)(h0 + (size_t)(pbase + pt) * 128 + chk * 8) = m;
  }
}

// ---- K4: pos stage, per-wave 32 rows of h0 -> 2 res_blocks -> h1 (f32) ----
__global__ __launch_bounds__(128, 2) void k_pos(
    const _Float16* __restrict__ h0, const _Float16* __restrict__ wp,
    const float* __restrict__ b1, const float* __restrict__ g1, const float* __restrict__ bb1,
    const float* __restrict__ b2, const float* __restrict__ g2, const float* __restrict__ bb2,
    float* __restrict__ h1) {
  __shared__ _Float16 lds[2][32 * 128];
  const int wid = threadIdx.x >> 6, lane = threadIdx.x & 63;
  _Float16* L = lds[wid];
  const int wgl = blockIdx.x * 2 + wid;
  const size_t rowbase = (size_t)wgl * 32;
  #pragma unroll
  for (int i = 0; i < 8; ++i) {
    const int r = i * 4 + (lane >> 4), ch = lane & 15;
    const half8 tv = *(const half8*)(h0 + (rowbase + r) * 128 + ch * 8);
    stA(L, r, ch, tv);
  }
  __threadfence_block();
  const int g = lane >> 4, cr = lane & 15;
  half8 xres[2][4];
  #pragma unroll
  for (int mt = 0; mt < 2; ++mt)
    #pragma unroll
    for (int q = 0; q < 4; ++q)
      xres[mt][q] = ldA(L, mt * 16 + 4 * g + q, cr);
  res_block_dev<2, 0>(L, wp + 73728,  wp + 92160,  b1,       g1,       bb1,       b2,       g2,       bb2,       xres, lane, nullptr);
  res_block_dev<2, 2>(L, wp + 110592, wp + 129024, b1 + 128, g1 + 128, bb1 + 128, b2 + 128, g2 + 128, bb2 + 128, xres, lane, h1 + rowbase * 128);
}

// ---- K5: gather new_features (h1 by fps_idx, float4) + new_xyz ----
__global__ __launch_bounds__(256) void k_gather(const float* __restrict__ h1, const float* __restrict__ xyz,
                                                const int* __restrict__ fps, float* __restrict__ out) {
  const int i = blockIdx.x * 256 + threadIdx.x;
  const int FEAT4 = 8 * 1024 * 32;
  if (i < FEAT4) {
    const int c4 = i & 31, m = (i >> 5) & 1023, b = i >> 15;
    const int n = fps[b * 1024 + m];
    const f32x4 v = *(const f32x4*)(h1 + ((size_t)(b * 2048 + n)) * 128 + c4 * 4);
    *(f32x4*)(out + (size_t)i * 4) = v;
  } else {
    const int jj = i - FEAT4;
    if (jj < 8 * 1024 * 3) {
      const int dd = jj % 3, m = (jj / 3) & 1023, b = jj / 3072;
      const int n = fps[b * 1024 + m];
      out[8 * 1024 * 128 + jj] = xyz[((size_t)(b * 2048 + n)) * 3 + dd];
    }
  }
}

extern "C" void kernel_launch(void* const* d_in, const int* in_sizes, int n_in,
                              void* d_out, int out_size, void* d_ws, size_t ws_size,
                              hipStream_t stream) {
  const float* features = (const float*)d_in[0];
  const float* xyz      = (const float*)d_in[1];
  const int*   fps      = (const int*)d_in[2];
  const float* alpha    = (const float*)d_in[3];
  const float* beta     = (const float*)d_in[4];
  const float* pre_w1   = (const float*)d_in[5];
  const float* pre_b1   = (const float*)d_in[6];
  const float* pre_g1   = (const float*)d_in[7];
  const float* pre_bb1  = (const float*)d_in[8];
  const float* pre_w2   = (const float*)d_in[9];
  const float* pre_b2   = (const float*)d_in[10];
  const float* pre_g2   = (const float*)d_in[11];
  const float* pre_bb2  = (const float*)d_in[12];
  const float* pos_w1   = (const float*)d_in[13];
  const float* pos_b1   = (const float*)d_in[14];
  const float* pos_g1   = (const float*)d_in[15];
  const float* pos_bb1  = (const float*)d_in[16];
  const float* pos_w2   = (const float*)d_in[17];
  const float* pos_b2   = (const float*)d_in[18];
  const float* pos_g2   = (const float*)d_in[19];
  const float* pos_bb2  = (const float*)d_in[20];
  (void)in_sizes; (void)n_in; (void)out_size; (void)ws_size;

  char* ws = (char*)d_ws;                     // needs ~14.3 MB
  _Float16* wp   = (_Float16*)(ws);           // [0, 294912)
  int*      idxb = (int*)(ws + 524288);       // [512K, 2M)
  _Float16* h0   = (_Float16*)(ws + 2097152); // [2M, 6M)
  float*    h1   = (float*)(ws + 6291456);    // [6M, 14M)

  k_pack<<<dim3(576), dim3(256), 0, stream>>>(pre_w1, pre_w2, pos_w1, pos_w2, wp);
  k_knn<<<dim3(4096), dim3(256), 0, stream>>>(xyz, idxb);
  k_pre<<<dim3(4096), dim3(256), 0, stream>>>(features, idxb, wp, alpha, beta,
      pre_b1, pre_g1, pre_bb1, pre_b2, pre_g2, pre_bb2, h0);
  k_pos<<<dim3(256), dim3(128), 0, stream>>>(h0, wp,
      pos_b1, pos_g1, pos_bb1, pos_b2, pos_g2, pos_bb2, h1);
  k_gather<<<dim3(1120), dim3(256), 0, stream>>>(h1, xyz, fps, (float*)d_out);
}

// Round 12
// 194.574 us; speedup vs baseline: 1.0538x; 1.0538x over previous
//
#include <hip/hip_runtime.h>

// PointMLP stage: KNN(24) -> groupnorm+concat -> 2x res_block (D=128) -> max over K
//                 -> 2x res_block -> gather by fps_idx.
// fp16 MFMA (16x16x32).
// R12 A/B: k_pre split into two dispatches (half the points each) to compare in one bench:
//  A (pts 0..8191):  R6 champion structure — 2 pts/wave, 9-tile W (rowsum LN), wave-private
//     48-row slab, (256,2) [VGPR capped 128 -> ~40MB spill accepted], barrier-free. 116us full-grid.
//  B (pts 8192..16383): 1 pt/wave, barrier-free AND no-spill — xres removed via X/H ping-pong
//     LDS regions (residual re-read from LDS), acc 2x8x4=64 + bfr 16 ~= 115 VGPR fits 128 cap,
//     DPP mean+var, zero __syncthreads. 64KB LDS -> 2 blocks (8 waves)/CU.
// Perf law (R6-R11): k_pre is latency-bound; barriers hurt more than occupancy helps;
//  B-operand L2 traffic floor ~18KB/pt/GEMM at 2pts/wave (doubles at 1pt/wave).
// k_pos keeps the 9-tile rowsum-LN path. KNN: u64 threshold+compact+bitonic (R5).
// ws: wp[0,294912) fp16 weights (9 tiles/matrix); idx[512K,2M); h0[2M,6M) f16; h1[6M,14M) f32.

typedef _Float16 half8 __attribute__((ext_vector_type(8)));
typedef _Float16 h2v   __attribute__((ext_vector_type(2)));
typedef float    f32x4 __attribute__((ext_vector_type(4)));
typedef unsigned long long u64;

#define DEVINL __device__ __forceinline__

union H8 { half8 v; h2v p[4]; int w[4]; };

DEVINL f32x4 splat4(float s) { f32x4 r = {s, s, s, s}; return r; }

DEVINL _Float16 hmax1(_Float16 a, _Float16 b) { return a > b ? a : b; }
DEVINL h2v hmax2v(h2v a, h2v b) {
  h2v r; r[0] = hmax1(a[0], b[0]); r[1] = hmax1(a[1], b[1]); return r;
}
DEVINL h2v cvt2h(float lo, float hi) {
  return __builtin_bit_cast(h2v, __builtin_amdgcn_cvt_pkrtz(lo, hi));
}
DEVINL half8 hmax8(half8 a, half8 b) {
  H8 A, B, R; A.v = a; B.v = b;
  #pragma unroll
  for (int e = 0; e < 4; ++e) R.p[e] = hmax2v(A.p[e], B.p[e]);
  return R.v;
}
DEVINL half8 shfl_h8(half8 x, int m) {
  H8 X; X.v = x;
  #pragma unroll
  for (int e = 0; e < 4; ++e) X.w[e] = __shfl_xor(X.w[e], m);
  return X.v;
}

// 16-lane (DPP row) all-reduce add.
DEVINL float dpp_add16(float x) {
  int v = __builtin_bit_cast(int, x);
  x += __builtin_bit_cast(float, __builtin_amdgcn_update_dpp(v, v, 0xB1, 0xF, 0xF, true));
  v = __builtin_bit_cast(int, x);
  x += __builtin_bit_cast(float, __builtin_amdgcn_update_dpp(v, v, 0x4E, 0xF, 0xF, true));
  v = __builtin_bit_cast(int, x);
  x += __builtin_bit_cast(float, __builtin_amdgcn_update_dpp(v, v, 0x141, 0xF, 0xF, true));
  v = __builtin_bit_cast(int, x);
  x += __builtin_bit_cast(float, __builtin_amdgcn_update_dpp(v, v, 0x140, 0xF, 0xF, true));
  return x;
}

// ---- swizzled LDS helpers: row stride 256B, XOR 16B-chunk swizzle with (row&7) ----
DEVINL void stH(_Float16* L, int row, int col, _Float16 v) {
  const int b2 = col * 2;
  *(_Float16*)((char*)L + row * 256 + (((b2 >> 4) ^ (row & 7)) << 4) + (b2 & 15)) = v;
}
DEVINL half8 ldA(const _Float16* L, int row, int ch) {
  return *(const half8*)((const char*)L + row * 256 + ((ch ^ (row & 7)) << 4));
}
DEVINL void stA(_Float16* L, int row, int ch, half8 v) {
  *(half8*)((char*)L + row * 256 + ((ch ^ (row & 7)) << 4)) = v;
}

// ---- A(LDS) @ B(global, 9-tile incl rowsum): k_preA + k_pos ----
template<int MT>
DEVINL void mm_dev(const _Float16* L, const _Float16* __restrict__ W, f32x4 acc[MT][9], int lane) {
  const int g = lane >> 4, r = lane & 15;
  #pragma unroll
  for (int s = 0; s < 4; ++s) {
    half8 bfr[9];
    #pragma unroll
    for (int t = 0; t < 9; ++t)
      bfr[t] = *(const half8*)(W + (((s * 9 + t) * 64 + lane) * 8));
    #pragma unroll
    for (int mt = 0; mt < MT; ++mt) {
      const half8 a = ldA(L, mt * 16 + r, s * 4 + g);
      #pragma unroll
      for (int t = 0; t < 9; ++t)
        acc[mt][t] = __builtin_amdgcn_mfma_f32_16x16x32_f16(a, bfr[t], acc[mt][t], 0, 0, 0);
    }
  }
}

// ---- bias + LN with rowsum tile, 1-fma normalize (k_preA + k_pos) ----
template<int MT>
DEVINL void epi_ln(f32x4 acc[MT][9], const float* __restrict__ bv, const float* __restrict__ gv,
                   const float* __restrict__ bbv, int lane) {
  const int cr = lane & 15;
  const f32x4 bp0 = *(const f32x4*)(bv + cr * 8),  bp1 = *(const f32x4*)(bv + cr * 8 + 4);
  const f32x4 gp0 = *(const f32x4*)(gv + cr * 8),  gp1 = *(const f32x4*)(gv + cr * 8 + 4);
  const f32x4 ap0 = *(const f32x4*)(bbv + cr * 8), ap1 = *(const f32x4*)(bbv + cr * 8 + 4);
  const f32x4 bs4 = bp0 + bp1;
  const float sb = dpp_add16(bs4[0] + bs4[1] + bs4[2] + bs4[3]);
  #pragma unroll
  for (int mt = 0; mt < MT; ++mt) {
    f32x4 sq4 = splat4(0.f);
    #pragma unroll
    for (int t = 0; t < 8; ++t) {
      const float bias = (t < 4) ? bp0[t & 3] : bp1[t & 3];
      acc[mt][t] = acc[mt][t] + splat4(bias);
      sq4 = sq4 + acc[mt][t] * acc[mt][t];
    }
    #pragma unroll
    for (int q = 0; q < 4; ++q) sq4[q] = dpp_add16(sq4[q]);
    const f32x4 mean = (acc[mt][8] + splat4(sb)) * splat4(1.f / 128.f);
    f32x4 rstd;
    #pragma unroll
    for (int q = 0; q < 4; ++q) {
      const float var = fmaxf(sq4[q] * (1.f / 128.f) - mean[q] * mean[q], 0.f);
      rstd[q] = rsqrtf(var + 1e-5f);
    }
    #pragma unroll
    for (int t = 0; t < 8; ++t) {
      const float gs = (t < 4) ? gp0[t & 3] : gp1[t & 3];
      const float as = (t < 4) ? ap0[t & 3] : ap1[t & 3];
      const f32x4 c1 = rstd * splat4(gs);
      const f32x4 c0 = splat4(as) - mean * c1;
      acc[mt][t] = acc[mt][t] * c1 + c0;
    }
  }
}

// ---- res_block (global 9-tile W). MODE 0: rows to LDS + xres; 1: xres only; 2: f32 to gdst ----
template<int MT, int MODE>
DEVINL void res_block_dev(_Float16* L, const _Float16* __restrict__ W1, const _Float16* __restrict__ W2,
                          const float* b1, const float* g1, const float* bb1,
                          const float* b2, const float* g2, const float* bb2,
                          half8 xres[MT][4], int lane, float* __restrict__ gdst) {
  const int g = lane >> 4, cr = lane & 15;
  const h2v zero2 = {(_Float16)0, (_Float16)0};
  f32x4 acc[MT][9];
  #pragma unroll
  for (int mt = 0; mt < MT; ++mt)
    #pragma unroll
    for (int t = 0; t < 9; ++t) acc[mt][t] = splat4(0.f);
  mm_dev<MT>(L, W1, acc, lane);
  epi_ln<MT>(acc, b1, g1, bb1, lane);
  __threadfence_block();
  #pragma unroll
  for (int mt = 0; mt < MT; ++mt)
    #pragma unroll
    for (int q = 0; q < 4; ++q) {
      H8 hv;
      #pragma unroll
      for (int e = 0; e < 4; ++e)
        hv.p[e] = hmax2v(cvt2h(acc[mt][2 * e][q], acc[mt][2 * e + 1][q]), zero2);
      stA(L, mt * 16 + 4 * g + q, cr, hv.v);
    }
  #pragma unroll
  for (int mt = 0; mt < MT; ++mt)
    #pragma unroll
    for (int t = 0; t < 9; ++t) acc[mt][t] = splat4(0.f);
  __threadfence_block();
  mm_dev<MT>(L, W2, acc, lane);
  epi_ln<MT>(acc, b2, g2, bb2, lane);
  if constexpr (MODE == 0) __threadfence_block();
  #pragma unroll
  for (int mt = 0; mt < MT; ++mt)
    #pragma unroll
    for (int q = 0; q < 4; ++q) {
      const int row = mt * 16 + 4 * g + q;
      if constexpr (MODE == 2) {
        f32x4 lo, hi;
        #pragma unroll
        for (int e = 0; e < 4; ++e) {
          lo[e] = fmaxf(acc[mt][e][q]     + (float)xres[mt][q][e],     0.f);
          hi[e] = fmaxf(acc[mt][e + 4][q] + (float)xres[mt][q][e + 4], 0.f);
        }
        *(f32x4*)(gdst + row * 128 + cr * 8)     = lo;
        *(f32x4*)(gdst + row * 128 + cr * 8 + 4) = hi;
      } else {
        H8 s;
        #pragma unroll
        for (int e = 0; e < 4; ++e)
          s.p[e] = cvt2h(acc[mt][2 * e][q], acc[mt][2 * e + 1][q]);
        H8 z; z.v = s.v + xres[mt][q];
        #pragma unroll
        for (int e = 0; e < 4; ++e) z.p[e] = hmax2v(z.p[e], zero2);
        xres[mt][q] = z.v;
        if constexpr (MODE == 0) stA(L, row, cr, z.v);
      }
    }
  if constexpr (MODE == 0) __threadfence_block();
}

// ---- k_preB: one GEMM (A from src) + LN (+residual from rsrc) + relu -> f16 rows to dst.
// MT=2 (32 rows, 24 valid), full 8 tiles, bfr sub-batched 4+4, DPP mean+var, no barriers. ----
template<bool RES>
DEVINL void gemm_ln_B(const _Float16* src, _Float16* dst, const _Float16* rsrc,
                      const _Float16* __restrict__ W,
                      const float* __restrict__ bv, const float* __restrict__ gv,
                      const float* __restrict__ bbv, int lane) {
  const int g = lane >> 4, r = lane & 15, cr = r;
  const h2v zero2 = {(_Float16)0, (_Float16)0};
  f32x4 acc[2][8];
  #pragma unroll
  for (int mt = 0; mt < 2; ++mt)
    #pragma unroll
    for (int t = 0; t < 8; ++t) acc[mt][t] = splat4(0.f);
  #pragma unroll
  for (int s = 0; s < 4; ++s) {
    const half8 a0 = ldA(src, r,      s * 4 + g);
    const half8 a1 = ldA(src, 16 + r, s * 4 + g);
    #pragma unroll
    for (int hb = 0; hb < 2; ++hb) {
      half8 bfr[4];
      #pragma unroll
      for (int t = 0; t < 4; ++t)
        bfr[t] = *(const half8*)(W + (((s * 9 + hb * 4 + t) * 64 + lane) * 8));
      #pragma unroll
      for (int t = 0; t < 4; ++t) {
        acc[0][hb * 4 + t] = __builtin_amdgcn_mfma_f32_16x16x32_f16(a0, bfr[t], acc[0][hb * 4 + t], 0, 0, 0);
        acc[1][hb * 4 + t] = __builtin_amdgcn_mfma_f32_16x16x32_f16(a1, bfr[t], acc[1][hb * 4 + t], 0, 0, 0);
      }
    }
  }
  const f32x4 bp0 = *(const f32x4*)(bv + cr * 8),  bp1 = *(const f32x4*)(bv + cr * 8 + 4);
  const f32x4 gp0 = *(const f32x4*)(gv + cr * 8),  gp1 = *(const f32x4*)(gv + cr * 8 + 4);
  const f32x4 ap0 = *(const f32x4*)(bbv + cr * 8), ap1 = *(const f32x4*)(bbv + cr * 8 + 4);
  #pragma unroll
  for (int mt = 0; mt < 2; ++mt) {
    f32x4 su4 = splat4(0.f), sq4 = splat4(0.f);
    #pragma unroll
    for (int t = 0; t < 8; ++t) {
      const float bias = (t < 4) ? bp0[t & 3] : bp1[t & 3];
      const f32x4 x = acc[mt][t] + splat4(bias);
      acc[mt][t] = x;
      su4 = su4 + x;
      sq4 = sq4 + x * x;
    }
    #pragma unroll
    for (int q = 0; q < 4; ++q) { su4[q] = dpp_add16(su4[q]); sq4[q] = dpp_add16(sq4[q]); }
    #pragma unroll
    for (int q = 0; q < 4; ++q) {
      const int row = mt * 16 + 4 * g + q;
      const float mean = su4[q] * (1.f / 128.f);
      const float var  = fmaxf(sq4[q] * (1.f / 128.f) - mean * mean, 0.f);
      const float rstd = rsqrtf(var + 1e-5f);
      float y[8];
      #pragma unroll
      for (int t = 0; t < 8; ++t) {
        const float gs = (t < 4) ? gp0[t & 3] : gp1[t & 3];
        const float as = (t < 4) ? ap0[t & 3] : ap1[t & 3];
        const float c1 = rstd * gs;
        const float c0 = as - mean * c1;
        y[t] = fmaf(acc[mt][t][q], c1, c0);
      }
      if constexpr (RES) {
        const half8 xv = ldA(rsrc, row, cr);     // read BEFORE overwrite (same lane/addr)
        #pragma unroll
        for (int t = 0; t < 8; ++t) y[t] += (float)xv[t];
      }
      H8 o;
      #pragma unroll
      for (int e = 0; e < 4; ++e)
        o.p[e] = hmax2v(cvt2h(y[2 * e], y[2 * e + 1]), zero2);
      stA(dst, row, cr, o.v);
    }
  }
}

// ---- K0: pack 8 weight matrices into 9-tile fp16 B-fragment order (tile 8 = rowsum bcast) ----
__global__ __launch_bounds__(256) void k_pack(const float* __restrict__ preW1, const float* __restrict__ preW2,
                                              const float* __restrict__ posW1, const float* __restrict__ posW2,
                                              _Float16* __restrict__ wp) {
  const int o = blockIdx.x * 256 + threadIdx.x;   // 147456 total (576 blocks)
  const int mat = o / 18432, rem = o % 18432;
  const int frag = rem >> 9, li = (rem >> 3) & 63, j = rem & 7;
  const int s = frag / 9, t = frag % 9;
  const int k = s * 32 + ((li >> 4) << 3) + j;
  const int blk = (mat >> 1) & 1, which = mat & 1;
  const float* base = (mat < 4) ? (which ? preW2 : preW1) : (which ? posW2 : posW1);
  const float* Wm = base + blk * 16384;
  float val;
  if (t < 8) {
    val = Wm[k * 128 + (li & 15) * 8 + t];
  } else {
    float ssum = 0.f;
    for (int n = 0; n < 128; ++n) ssum += Wm[k * 128 + n];
    val = ssum;
  }
  wp[o] = (_Float16)val;
}

// ---- KNN helpers ----
DEVINL u64 kmin(u64 a, u64 b) { return a < b ? a : b; }
DEVINL u64 kmax(u64 a, u64 b) { return a > b ? a : b; }
DEVINL u64 min8(const u64* k) {
  u64 a = kmin(k[0], k[1]), b = kmin(k[2], k[3]);
  u64 c = kmin(k[4], k[5]), d = kmin(k[6], k[7]);
  return kmin(kmin(a, b), kmin(c, d));
}
DEVINL void inv8(u64* k, int j) {
  #pragma unroll
  for (int s = 0; s < 8; ++s) k[s] = (s == j) ? ~0ULL : k[s];
}
DEVINL u64 bitonic64(u64 v, int lane) {
  #pragma unroll
  for (int k = 2; k <= 64; k <<= 1) {
    #pragma unroll
    for (int j = k >> 1; j > 0; j >>= 1) {
      const u64 o = __shfl_xor(v, j);
      const bool up = ((lane & k) == 0);
      const bool lower = ((lane & j) == 0);
      v = (lower == up) ? kmin(v, o) : kmax(v, o);
    }
  }
  return v;
}

// ---- K1: exact 24-NN per point, tie-break = smaller index (u64 lex order) ----
__global__ __launch_bounds__(256) void k_knn(const float* __restrict__ xyz, int* __restrict__ idxout) {
  __shared__ float sx[2048], sy[2048], sz[2048];
  __shared__ u64 scand[4][64];
  const int b = blockIdx.x >> 9;
  const int qbase = (blockIdx.x & 511) * 4;
  const float* xb = xyz + (size_t)b * 2048 * 3;
  for (int i = threadIdx.x; i < 2048; i += 256) {
    sx[i] = xb[i * 3 + 0]; sy[i] = xb[i * 3 + 1]; sz[i] = xb[i * 3 + 2];
  }
  __syncthreads();
  const int wid = threadIdx.x >> 6, lane = threadIdx.x & 63;
  const int q = qbase + wid;
  const float qx = sx[q], qy = sy[q], qz = sz[q];
  const float q2 = qx * qx + qy * qy + qz * qz;
  u64 key[32];
  u64 lmin = ~0ULL;
  #pragma unroll
  for (int j = 0; j < 32; ++j) {
    const int m = j * 64 + lane;
    const float mx = sx[m], my = sy[m], mz = sz[m];
    const float m2 = mx * mx + my * my + mz * mz;
    const float d = fmaxf(q2 + m2 - 2.f * (qx * mx + qy * my + qz * mz), 0.f);
    key[j] = ((u64)__builtin_bit_cast(unsigned, d) << 32) | (unsigned)m;
    lmin = kmin(lmin, key[j]);
  }
  const u64 t = __shfl(bitonic64(lmin, lane), 23);
  int c = 0;
  #pragma unroll
  for (int j = 0; j < 32; ++j) c += (key[j] <= t) ? 1 : 0;
  int inc = c;
  #pragma unroll
  for (int off = 1; off < 64; off <<= 1) {
    const int n = __shfl_up(inc, off);
    if (lane >= off) inc += n;
  }
  const int T = __shfl(inc, 63);
  if (T <= 64) {
    int idx = inc - c;
    #pragma unroll
    for (int j = 0; j < 32; ++j)
      if (key[j] <= t) { scand[wid][idx] = key[j]; ++idx; }
    __threadfence_block();
    u64 cand = (lane < T) ? scand[wid][lane] : ~0ULL;
    cand = bitonic64(cand, lane);
    if (lane < 24) idxout[(size_t)(b * 2048 + q) * 24 + lane] = (int)(unsigned)cand;
  } else {
    u64 gk[4];
    #pragma unroll
    for (int g4 = 0; g4 < 4; ++g4) gk[g4] = min8(key + g4 * 8);
    int keep = 0;
    #pragma unroll 1
    for (int r = 0; r < 24; ++r) {
      u64 kk = kmin(kmin(gk[0], gk[1]), kmin(gk[2], gk[3]));
      #pragma unroll
      for (int off = 32; off >= 1; off >>= 1) kk = kmin(__shfl_xor(kk, off), kk);
      const unsigned wm = (unsigned)kk;
      if (lane == r) keep = (int)wm;
      if (lane == (int)(wm & 63)) {
        const int j = (int)(wm >> 6);
        if (j < 16) {
          if (j < 8) { inv8(key,      j);      gk[0] = min8(key);      }
          else       { inv8(key + 8,  j - 8);  gk[1] = min8(key + 8);  }
        } else {
          if (j < 24){ inv8(key + 16, j - 16); gk[2] = min8(key + 16); }
          else       { inv8(key + 24, j - 24); gk[3] = min8(key + 24); }
        }
      }
    }
    if (lane < 24) idxout[(size_t)(b * 2048 + q) * 24 + lane] = keep;
  }
}

// ---- K3a: R6 champion — per-wave 2 points (48 rows), wave-private, (256,2)+spill ----
__global__ __launch_bounds__(256, 2) void k_preA(
    const float* __restrict__ features, const int* __restrict__ idxin,
    const _Float16* __restrict__ wp, const float* __restrict__ alpha, const float* __restrict__ beta,
    const float* __restrict__ b1, const float* __restrict__ g1, const float* __restrict__ bb1,
    const float* __restrict__ b2, const float* __restrict__ g2, const float* __restrict__ bb2,
    _Float16* __restrict__ h0, int pbase0) {
  __shared__ _Float16 lds[4][48 * 128];
  const int wid = threadIdx.x >> 6, lane = threadIdx.x & 63;
  _Float16* L = lds[wid];
  const int wgl = blockIdx.x * 4 + wid;
  const int p0 = pbase0 + wgl * 2;
  const int b = p0 >> 11;
  const float* fb = features + (size_t)b * 2048 * 64;
  {
    const int c = lane;
    const float al = alpha[c], be = beta[c];
    #pragma unroll 1
    for (int pp = 0; pp < 2; ++pp) {
      const int p = p0 + pp;
      const int n = p & 2047;
      const int* ip = idxin + (size_t)p * 24;
      const float center = fb[n * 64 + c];
      float v[24]; float su = 0.f, sq = 0.f;
      #pragma unroll
      for (int k = 0; k < 24; ++k) {
        v[k] = fb[ip[k] * 64 + c];
        su += v[k]; sq = fmaf(v[k], v[k], sq);
      }
      const float mean = su * (1.f / 24.f);
      const float var = fmaxf((sq - 24.f * mean * mean) * (1.f / 23.f), 0.f);
      const float rs = 1.f / fmaxf(sqrtf(var), 1e-6f);
      const float c1 = rs * al;
      const float c0 = be - mean * c1 - center;
      const _Float16 ch = (_Float16)center;
      #pragma unroll
      for (int k = 0; k < 24; ++k) {
        const int row = pp * 24 + k;
        stH(L, row, c, ch);
        stH(L, row, 64 + c, (_Float16)fmaf(v[k], c1, c0));
      }
    }
  }
  __threadfence_block();
  const int g = lane >> 4, cr = lane & 15;
  half8 xres[3][4];
  #pragma unroll
  for (int mt = 0; mt < 3; ++mt)
    #pragma unroll
    for (int q = 0; q < 4; ++q)
      xres[mt][q] = ldA(L, mt * 16 + 4 * g + q, cr);
  res_block_dev<3, 0>(L, wp,         wp + 18432,
                      b1,       g1,       bb1,       b2,       g2,       bb2,       xres, lane, nullptr);
  res_block_dev<3, 1>(L, wp + 36864, wp + 55296,
                      b1 + 128, g1 + 128, bb1 + 128, b2 + 128, g2 + 128, bb2 + 128, xres, lane, nullptr);
  // max over the 24 rows of each point (rows 0..23 -> p0, 24..47 -> p0+1), all in f16
  half8 m0 = hmax8(hmax8(xres[0][0], xres[0][1]), hmax8(xres[0][2], xres[0][3]));
  m0 = hmax8(m0, shfl_h8(m0, 16));
  m0 = hmax8(m0, shfl_h8(m0, 32));
  half8 m1 = hmax8(hmax8(xres[1][0], xres[1][1]), hmax8(xres[1][2], xres[1][3]));
  m1 = hmax8(m1, shfl_h8(m1, 16));          // g0/g1 hold rows16..23 (p0); g2/g3 rows24..31 (p1)
  const half8 m1o = shfl_h8(m1, 32);        // bring p1-part to g0/g1 side
  half8 m2 = hmax8(hmax8(xres[2][0], xres[2][1]), hmax8(xres[2][2], xres[2][3]));
  m2 = hmax8(m2, shfl_h8(m2, 16));
  m2 = hmax8(m2, shfl_h8(m2, 32));
  if (g == 0) *(half8*)(h0 + (size_t)p0 * 128 + cr * 8)       = hmax8(m0, m1);
  if (g == 1) *(half8*)(h0 + (size_t)(p0 + 1) * 128 + cr * 8) = hmax8(m2, m1o);
}

// ---- K3b: no-spill barrier-free — 1 point/wave, X/H ping-pong LDS, DPP LN ----
__global__ __launch_bounds__(256, 2) void k_preB(
    const float* __restrict__ features, const int* __restrict__ idxin,
    const _Float16* __restrict__ wp, const float* __restrict__ alpha, const float* __restrict__ beta,
    const float* __restrict__ b1, const float* __restrict__ g1, const float* __restrict__ bb1,
    const float* __restrict__ b2, const float* __restrict__ g2, const float* __restrict__ bb2,
    _Float16* __restrict__ h0, int pbase0) {
  __shared__ _Float16 AB[4][2][32 * 128];   // 64KB
  const int tid = threadIdx.x, wid = tid >> 6, lane = tid & 63;
  _Float16* Xr = AB[wid][0];
  _Float16* Hr = AB[wid][1];
  const int p = pbase0 + blockIdx.x * 4 + wid;
  const int b = p >> 11, n = p & 2047;
  const float* fb = features + (size_t)b * 2048 * 64;
  {
    const int c = lane;                     // lane == channel (C=64)
    const float al = alpha[c], be = beta[c];
    const int* ip = idxin + (size_t)p * 24;
    const float center = fb[n * 64 + c];
    float v[24]; float su = 0.f, sq = 0.f;
    #pragma unroll
    for (int k = 0; k < 24; ++k) {
      v[k] = fb[ip[k] * 64 + c];
      su += v[k]; sq = fmaf(v[k], v[k], sq);
    }
    const float mean = su * (1.f / 24.f);
    const float var = fmaxf((sq - 24.f * mean * mean) * (1.f / 23.f), 0.f);
    const float rs = 1.f / fmaxf(sqrtf(var), 1e-6f);
    const float c1 = rs * al;
    const float c0 = be - mean * c1 - center;
    const _Float16 ch = (_Float16)center;
    #pragma unroll
    for (int k = 0; k < 24; ++k) {
      stH(Xr, k, c, ch);
      stH(Xr, k, 64 + c, (_Float16)fmaf(v[k], c1, c0));
    }
    const _Float16 z0 = (_Float16)0;        // zero padding rows 24..31
    #pragma unroll
    for (int k = 24; k < 32; ++k) {
      stH(Xr, k, c, z0);
      stH(Xr, k, 64 + c, z0);
    }
  }
  __threadfence_block();
  gemm_ln_B<false>(Xr, Hr, nullptr, wp,         b1,       g1,       bb1,       lane);
  __threadfence_block();
  gemm_ln_B<true >(Hr, Xr, Xr,      wp + 18432, b2,       g2,       bb2,       lane);
  __threadfence_block();
  gemm_ln_B<false>(Xr, Hr, nullptr, wp + 36864, b1 + 128, g1 + 128, bb1 + 128, lane);
  __threadfence_block();
  gemm_ln_B<true >(Hr, Xr, Xr,      wp + 55296, b2 + 128, g2 + 128, bb2 + 128, lane);
  __threadfence_block();
  // K-max: lane (gq, cr) -> rows gq*6..gq*6+5, chunk cr; reduce over gq
  const int gq = lane >> 4, cr = lane & 15;
  half8 m = ldA(Xr, gq * 6, cr);
  #pragma unroll
  for (int k = 1; k < 6; ++k) m = hmax8(m, ldA(Xr, gq * 6 + k, cr));
  m = hmax8(m, shfl_h8(m, 16));
  m = hmax8(m, shfl_h8(m, 32));
  if (gq == 0) *(half8*)(h0 + (size_t)p * 128 + cr * 8) = m;
}

// ---- K4: pos stage, per-wave 32 rows of h0 -> 2 res_blocks -> h1 (f32) ----
__global__ __launch_bounds__(128, 2) void k_pos(
    const _Float16* __restrict__ h0, const _Float16* __restrict__ wp,
    const float* __restrict__ b1, const float* __restrict__ g1, const float* __restrict__ bb1,
    const float* __restrict__ b2, const float* __restrict__ g2, const float* __restrict__ bb2,
    float* __restrict__ h1) {
  __shared__ _Float16 lds[2][32 * 128];
  const int wid = threadIdx.x >> 6, lane = threadIdx.x & 63;
  _Float16* L = lds[wid];
  const int wgl = blockIdx.x * 2 + wid;
  const size_t rowbase = (size_t)wgl * 32;
  #pragma unroll
  for (int i = 0; i < 8; ++i) {
    const int r = i * 4 + (lane >> 4), ch = lane & 15;
    const half8 tv = *(const half8*)(h0 + (rowbase + r) * 128 + ch * 8);
    stA(L, r, ch, tv);
  }
  __threadfence_block();
  const int g = lane >> 4, cr = lane & 15;
  half8 xres[2][4];
  #pragma unroll
  for (int mt = 0; mt < 2; ++mt)
    #pragma unroll
    for (int q = 0; q < 4; ++q)
      xres[mt][q] = ldA(L, mt * 16 + 4 * g + q, cr);
  res_block_dev<2, 0>(L, wp + 73728,  wp + 92160,  b1,       g1,       bb1,       b2,       g2,       bb2,       xres, lane, nullptr);
  res_block_dev<2, 2>(L, wp + 110592, wp + 129024, b1 + 128, g1 + 128, bb1 + 128, b2 + 128, g2 + 128, bb2 + 128, xres, lane, h1 + rowbase * 128);
}

// ---- K5: gather new_features (h1 by fps_idx, float4) + new_xyz ----
__global__ __launch_bounds__(256) void k_gather(const float* __restrict__ h1, const float* __restrict__ xyz,
                                                const int* __restrict__ fps, float* __restrict__ out) {
  const int i = blockIdx.x * 256 + threadIdx.x;
  const int FEAT4 = 8 * 1024 * 32;
  if (i < FEAT4) {
    const int c4 = i & 31, m = (i >> 5) & 1023, b = i >> 15;
    const int n = fps[b * 1024 + m];
    const f32x4 v = *(const f32x4*)(h1 + ((size_t)(b * 2048 + n)) * 128 + c4 * 4);
    *(f32x4*)(out + (size_t)i * 4) = v;
  } else {
    const int jj = i - FEAT4;
    if (jj < 8 * 1024 * 3) {
      const int dd = jj % 3, m = (jj / 3) & 1023, b = jj / 3072;
      const int n = fps[b * 1024 + m];
      out[8 * 1024 * 128 + jj] = xyz[((size_t)(b * 2048 + n)) * 3 + dd];
    }
  }
}

extern "C" void kernel_launch(void* const* d_in, const int* in_sizes, int n_in,
                              void* d_out, int out_size, void* d_ws, size_t ws_size,
                              hipStream_t stream) {
  const float* features = (const float*)d_in[0];
  const float* xyz      = (const float*)d_in[1];
  const int*   fps      = (const int*)d_in[2];
  const float* alpha    = (const float*)d_in[3];
  const float* beta     = (const float*)d_in[4];
  const float* pre_w1   = (const float*)d_in[5];
  const float* pre_b1   = (const float*)d_in[6];
  const float* pre_g1   = (const float*)d_in[7];
  const float* pre_bb1  = (const float*)d_in[8];
  const float* pre_w2   = (const float*)d_in[9];
  const float* pre_b2   = (const float*)d_in[10];
  const float* pre_g2   = (const float*)d_in[11];
  const float* pre_bb2  = (const float*)d_in[12];
  const float* pos_w1   = (const float*)d_in[13];
  const float* pos_b1   = (const float*)d_in[14];
  const float* pos_g1   = (const float*)d_in[15];
  const float* pos_bb1  = (const float*)d_in[16];
  const float* pos_w2   = (const float*)d_in[17];
  const float* pos_b2   = (const float*)d_in[18];
  const float* pos_g2   = (const float*)d_in[19];
  const float* pos_bb2  = (const float*)d_in[20];
  (void)in_sizes; (void)n_in; (void)out_size; (void)ws_size;

  char* ws = (char*)d_ws;                     // needs ~14.3 MB
  _Float16* wp   = (_Float16*)(ws);           // [0, 294912)
  int*      idxb = (int*)(ws + 524288);       // [512K, 2M)
  _Float16* h0   = (_Float16*)(ws + 2097152); // [2M, 6M)
  float*    h1   = (float*)(ws + 6291456);    // [6M, 14M)

  k_pack<<<dim3(576), dim3(256), 0, stream>>>(pre_w1, pre_w2, pos_w1, pos_w2, wp);
  k_knn<<<dim3(4096), dim3(256), 0, stream>>>(xyz, idxb);
  k_preA<<<dim3(1024), dim3(256), 0, stream>>>(features, idxb, wp, alpha, beta,
      pre_b1, pre_g1, pre_bb1, pre_b2, pre_g2, pre_bb2, h0, 0);
  k_preB<<<dim3(2048), dim3(256), 0, stream>>>(features, idxb, wp, alpha, beta,
      pre_b1, pre_g1, pre_bb1, pre_b2, pre_g2, pre_bb2, h0, 8192);
  k_pos<<<dim3(256), dim3(128), 0, stream>>>(h0, wp,
      pos_b1, pos_g1, pos_bb1, pos_b2, pos_g2, pos_bb2, h1);
  k_gather<<<dim3(1120), dim3(256), 0, stream>>>(h1, xyz, fps, (float*)d_out);
}

// Round 13
// 170.388 us; speedup vs baseline: 1.2034x; 1.1419x over previous
//
#include <hip/hip_runtime.h>

// PointMLP stage: KNN(24) -> groupnorm+concat -> 2x res_block (D=128) -> max over K
//                 -> 2x res_block -> gather by fps_idx.
// fp16 MFMA (16x16x32).
// k_pre: R6/R12-A champion — 2 pts/wave (48 rows), 9-tile W (rowsum LN), wave-private
//   slab, barrier-free, (256,2). The 128-VGPR cap spills ~21 dwords/thread (cold xres
//   across GEMMs, ~50MB round trip, ~2% cost) — measured FASTER (116us) than every
//   no-spill variant (R7 142, R8 210, R9 157, R10/11 157): occupancy+W-amortization win.
// KNN: u64 keys; threshold via f32 lane-min bitonic (distance-monotonic, so f32 sort
//   suffices for the threshold; final u64 bitonic gives exact (dist,idx) order).
// k_pos keeps the 9-tile rowsum-LN path. ws: wp[0,294912) fp16 weights (9 tiles/mat);
// idx[512K,2M); h0[2M,6M) f16; h1[6M,14M) f32.

typedef _Float16 half8 __attribute__((ext_vector_type(8)));
typedef _Float16 h2v   __attribute__((ext_vector_type(2)));
typedef float    f32x4 __attribute__((ext_vector_type(4)));
typedef unsigned long long u64;

#define DEVINL __device__ __forceinline__

union H8 { half8 v; h2v p[4]; int w[4]; };

DEVINL f32x4 splat4(float s) { f32x4 r = {s, s, s, s}; return r; }

DEVINL _Float16 hmax1(_Float16 a, _Float16 b) { return a > b ? a : b; }
DEVINL h2v hmax2v(h2v a, h2v b) {
  h2v r; r[0] = hmax1(a[0], b[0]); r[1] = hmax1(a[1], b[1]); return r;
}
DEVINL h2v cvt2h(float lo, float hi) {
  return __builtin_bit_cast(h2v, __builtin_amdgcn_cvt_pkrtz(lo, hi));
}
DEVINL half8 hmax8(half8 a, half8 b) {
  H8 A, B, R; A.v = a; B.v = b;
  #pragma unroll
  for (int e = 0; e < 4; ++e) R.p[e] = hmax2v(A.p[e], B.p[e]);
  return R.v;
}
DEVINL half8 shfl_h8(half8 x, int m) {
  H8 X; X.v = x;
  #pragma unroll
  for (int e = 0; e < 4; ++e) X.w[e] = __shfl_xor(X.w[e], m);
  return X.v;
}

// 16-lane (DPP row) all-reduce add.
DEVINL float dpp_add16(float x) {
  int v = __builtin_bit_cast(int, x);
  x += __builtin_bit_cast(float, __builtin_amdgcn_update_dpp(v, v, 0xB1, 0xF, 0xF, true));
  v = __builtin_bit_cast(int, x);
  x += __builtin_bit_cast(float, __builtin_amdgcn_update_dpp(v, v, 0x4E, 0xF, 0xF, true));
  v = __builtin_bit_cast(int, x);
  x += __builtin_bit_cast(float, __builtin_amdgcn_update_dpp(v, v, 0x141, 0xF, 0xF, true));
  v = __builtin_bit_cast(int, x);
  x += __builtin_bit_cast(float, __builtin_amdgcn_update_dpp(v, v, 0x140, 0xF, 0xF, true));
  return x;
}

// ---- swizzled LDS helpers: row stride 256B, XOR 16B-chunk swizzle with (row&7) ----
DEVINL void stH(_Float16* L, int row, int col, _Float16 v) {
  const int b2 = col * 2;
  *(_Float16*)((char*)L + row * 256 + (((b2 >> 4) ^ (row & 7)) << 4) + (b2 & 15)) = v;
}
DEVINL half8 ldA(const _Float16* L, int row, int ch) {
  return *(const half8*)((const char*)L + row * 256 + ((ch ^ (row & 7)) << 4));
}
DEVINL void stA(_Float16* L, int row, int ch, half8 v) {
  *(half8*)((char*)L + row * 256 + ((ch ^ (row & 7)) << 4)) = v;
}

// ---- A(LDS) @ B(global, 9-tile incl rowsum) ----
template<int MT>
DEVINL void mm_dev(const _Float16* L, const _Float16* __restrict__ W, f32x4 acc[MT][9], int lane) {
  const int g = lane >> 4, r = lane & 15;
  #pragma unroll
  for (int s = 0; s < 4; ++s) {
    half8 bfr[9];
    #pragma unroll
    for (int t = 0; t < 9; ++t)
      bfr[t] = *(const half8*)(W + (((s * 9 + t) * 64 + lane) * 8));
    #pragma unroll
    for (int mt = 0; mt < MT; ++mt) {
      const half8 a = ldA(L, mt * 16 + r, s * 4 + g);
      #pragma unroll
      for (int t = 0; t < 9; ++t)
        acc[mt][t] = __builtin_amdgcn_mfma_f32_16x16x32_f16(a, bfr[t], acc[mt][t], 0, 0, 0);
    }
  }
}

// ---- bias + LN with rowsum tile, 1-fma normalize ----
template<int MT>
DEVINL void epi_ln(f32x4 acc[MT][9], const float* __restrict__ bv, const float* __restrict__ gv,
                   const float* __restrict__ bbv, int lane) {
  const int cr = lane & 15;
  const f32x4 bp0 = *(const f32x4*)(bv + cr * 8),  bp1 = *(const f32x4*)(bv + cr * 8 + 4);
  const f32x4 gp0 = *(const f32x4*)(gv + cr * 8),  gp1 = *(const f32x4*)(gv + cr * 8 + 4);
  const f32x4 ap0 = *(const f32x4*)(bbv + cr * 8), ap1 = *(const f32x4*)(bbv + cr * 8 + 4);
  const f32x4 bs4 = bp0 + bp1;
  const float sb = dpp_add16(bs4[0] + bs4[1] + bs4[2] + bs4[3]);
  #pragma unroll
  for (int mt = 0; mt < MT; ++mt) {
    f32x4 sq4 = splat4(0.f);
    #pragma unroll
    for (int t = 0; t < 8; ++t) {
      const float bias = (t < 4) ? bp0[t & 3] : bp1[t & 3];
      acc[mt][t] = acc[mt][t] + splat4(bias);
      sq4 = sq4 + acc[mt][t] * acc[mt][t];
    }
    #pragma unroll
    for (int q = 0; q < 4; ++q) sq4[q] = dpp_add16(sq4[q]);
    const f32x4 mean = (acc[mt][8] + splat4(sb)) * splat4(1.f / 128.f);
    f32x4 rstd;
    #pragma unroll
    for (int q = 0; q < 4; ++q) {
      const float var = fmaxf(sq4[q] * (1.f / 128.f) - mean[q] * mean[q], 0.f);
      rstd[q] = rsqrtf(var + 1e-5f);
    }
    #pragma unroll
    for (int t = 0; t < 8; ++t) {
      const float gs = (t < 4) ? gp0[t & 3] : gp1[t & 3];
      const float as = (t < 4) ? ap0[t & 3] : ap1[t & 3];
      const f32x4 c1 = rstd * splat4(gs);
      const f32x4 c0 = splat4(as) - mean * c1;
      acc[mt][t] = acc[mt][t] * c1 + c0;
    }
  }
}

// ---- res_block (global 9-tile W). MODE 0: rows to LDS + xres; 1: xres only; 2: f32 to gdst ----
template<int MT, int MODE>
DEVINL void res_block_dev(_Float16* L, const _Float16* __restrict__ W1, const _Float16* __restrict__ W2,
                          const float* b1, const float* g1, const float* bb1,
                          const float* b2, const float* g2, const float* bb2,
                          half8 xres[MT][4], int lane, float* __restrict__ gdst) {
  const int g = lane >> 4, cr = lane & 15;
  const h2v zero2 = {(_Float16)0, (_Float16)0};
  f32x4 acc[MT][9];
  #pragma unroll
  for (int mt = 0; mt < MT; ++mt)
    #pragma unroll
    for (int t = 0; t < 9; ++t) acc[mt][t] = splat4(0.f);
  mm_dev<MT>(L, W1, acc, lane);
  epi_ln<MT>(acc, b1, g1, bb1, lane);
  __threadfence_block();
  #pragma unroll
  for (int mt = 0; mt < MT; ++mt)
    #pragma unroll
    for (int q = 0; q < 4; ++q) {
      H8 hv;
      #pragma unroll
      for (int e = 0; e < 4; ++e)
        hv.p[e] = hmax2v(cvt2h(acc[mt][2 * e][q], acc[mt][2 * e + 1][q]), zero2);
      stA(L, mt * 16 + 4 * g + q, cr, hv.v);
    }
  #pragma unroll
  for (int mt = 0; mt < MT; ++mt)
    #pragma unroll
    for (int t = 0; t < 9; ++t) acc[mt][t] = splat4(0.f);
  __threadfence_block();
  mm_dev<MT>(L, W2, acc, lane);
  epi_ln<MT>(acc, b2, g2, bb2, lane);
  if constexpr (MODE == 0) __threadfence_block();
  #pragma unroll
  for (int mt = 0; mt < MT; ++mt)
    #pragma unroll
    for (int q = 0; q < 4; ++q) {
      const int row = mt * 16 + 4 * g + q;
      if constexpr (MODE == 2) {
        f32x4 lo, hi;
        #pragma unroll
        for (int e = 0; e < 4; ++e) {
          lo[e] = fmaxf(acc[mt][e][q]     + (float)xres[mt][q][e],     0.f);
          hi[e] = fmaxf(acc[mt][e + 4][q] + (float)xres[mt][q][e + 4], 0.f);
        }
        *(f32x4*)(gdst + row * 128 + cr * 8)     = lo;
        *(f32x4*)(gdst + row * 128 + cr * 8 + 4) = hi;
      } else {
        H8 s;
        #pragma unroll
        for (int e = 0; e < 4; ++e)
          s.p[e] = cvt2h(acc[mt][2 * e][q], acc[mt][2 * e + 1][q]);
        H8 z; z.v = s.v + xres[mt][q];
        #pragma unroll
        for (int e = 0; e < 4; ++e) z.p[e] = hmax2v(z.p[e], zero2);
        xres[mt][q] = z.v;
        if constexpr (MODE == 0) stA(L, row, cr, z.v);
      }
    }
  if constexpr (MODE == 0) __threadfence_block();
}

// ---- K0: pack 8 weight matrices into 9-tile fp16 B-fragment order (tile 8 = rowsum bcast) ----
__global__ __launch_bounds__(256) void k_pack(const float* __restrict__ preW1, const float* __restrict__ preW2,
                                              const float* __restrict__ posW1, const float* __restrict__ posW2,
                                              _Float16* __restrict__ wp) {
  const int o = blockIdx.x * 256 + threadIdx.x;   // 147456 total (576 blocks)
  const int mat = o / 18432, rem = o % 18432;
  const int frag = rem >> 9, li = (rem >> 3) & 63, j = rem & 7;
  const int s = frag / 9, t = frag % 9;
  const int k = s * 32 + ((li >> 4) << 3) + j;
  const int blk = (mat >> 1) & 1, which = mat & 1;
  const float* base = (mat < 4) ? (which ? preW2 : preW1) : (which ? posW2 : posW1);
  const float* Wm = base + blk * 16384;
  float val;
  if (t < 8) {
    val = Wm[k * 128 + (li & 15) * 8 + t];
  } else {
    float ssum = 0.f;
    for (int n = 0; n < 128; ++n) ssum += Wm[k * 128 + n];
    val = ssum;
  }
  wp[o] = (_Float16)val;
}

// ---- KNN helpers ----
DEVINL u64 kmin(u64 a, u64 b) { return a < b ? a : b; }
DEVINL u64 kmax(u64 a, u64 b) { return a > b ? a : b; }
DEVINL u64 min8(const u64* k) {
  u64 a = kmin(k[0], k[1]), b = kmin(k[2], k[3]);
  u64 c = kmin(k[4], k[5]), d = kmin(k[6], k[7]);
  return kmin(kmin(a, b), kmin(c, d));
}
DEVINL void inv8(u64* k, int j) {
  #pragma unroll
  for (int s = 0; s < 8; ++s) k[s] = (s == j) ? ~0ULL : k[s];
}
// 64-lane bitonic sort, one u64 per lane (exact (dist,idx) order).
DEVINL u64 bitonic64(u64 v, int lane) {
  #pragma unroll
  for (int k = 2; k <= 64; k <<= 1) {
    #pragma unroll
    for (int j = k >> 1; j > 0; j >>= 1) {
      const u64 o = __shfl_xor(v, j);
      const bool up = ((lane & k) == 0);
      const bool lower = ((lane & j) == 0);
      v = (lower == up) ? kmin(v, o) : kmax(v, o);
    }
  }
  return v;
}
// 64-lane bitonic sort, one f32 per lane (threshold only; dist-monotonic => valid).
DEVINL float bitonic64f(float v, int lane) {
  #pragma unroll
  for (int k = 2; k <= 64; k <<= 1) {
    #pragma unroll
    for (int j = k >> 1; j > 0; j >>= 1) {
      const float o = __shfl_xor(v, j);
      const bool up = ((lane & k) == 0);
      const bool lower = ((lane & j) == 0);
      v = (lower == up) ? fminf(v, o) : fmaxf(v, o);
    }
  }
  return v;
}

// ---- K1: exact 24-NN per point, tie-break = smaller index (u64 lex order) ----
__global__ __launch_bounds__(256) void k_knn(const float* __restrict__ xyz, int* __restrict__ idxout) {
  __shared__ float sx[2048], sy[2048], sz[2048];
  __shared__ u64 scand[4][64];
  const int b = blockIdx.x >> 9;
  const int qbase = (blockIdx.x & 511) * 4;
  const float* xb = xyz + (size_t)b * 2048 * 3;
  for (int i = threadIdx.x; i < 2048; i += 256) {
    sx[i] = xb[i * 3 + 0]; sy[i] = xb[i * 3 + 1]; sz[i] = xb[i * 3 + 2];
  }
  __syncthreads();
  const int wid = threadIdx.x >> 6, lane = threadIdx.x & 63;
  const int q = qbase + wid;
  const float qx = sx[q], qy = sy[q], qz = sz[q];
  const float q2 = qx * qx + qy * qy + qz * qz;
  u64 key[32];
  float dmin = 3.0e38f;
  #pragma unroll
  for (int j = 0; j < 32; ++j) {
    const int m = j * 64 + lane;
    const float mx = sx[m], my = sy[m], mz = sz[m];
    const float m2 = mx * mx + my * my + mz * mz;
    const float d = fmaxf(q2 + m2 - 2.f * (qx * mx + qy * my + qz * mz), 0.f);
    key[j] = ((u64)__builtin_bit_cast(unsigned, d) << 32) | (unsigned)m;
    dmin = fminf(dmin, d);
  }
  // threshold = 24th-smallest lane-min distance  =>  #(d <= tf) >= 24 and top-24 all <= tf
  const float tf = __shfl(bitonic64f(dmin, lane), 23);
  const u64 t = ((u64)__builtin_bit_cast(unsigned, tf) << 32) | 0xFFFFFFFFu;
  int c = 0;
  #pragma unroll
  for (int j = 0; j < 32; ++j) c += (key[j] <= t) ? 1 : 0;
  int inc = c;
  #pragma unroll
  for (int off = 1; off < 64; off <<= 1) {
    const int n = __shfl_up(inc, off);
    if (lane >= off) inc += n;
  }
  const int T = __shfl(inc, 63);
  if (T <= 64) {
    int idx = inc - c;
    #pragma unroll
    for (int j = 0; j < 32; ++j)
      if (key[j] <= t) { scand[wid][idx] = key[j]; ++idx; }
    __threadfence_block();
    u64 cand = (lane < T) ? scand[wid][lane] : ~0ULL;
    cand = bitonic64(cand, lane);
    if (lane < 24) idxout[(size_t)(b * 2048 + q) * 24 + lane] = (int)(unsigned)cand;
  } else {
    // exact fallback: 24-round tournament
    u64 gk[4];
    #pragma unroll
    for (int g4 = 0; g4 < 4; ++g4) gk[g4] = min8(key + g4 * 8);
    int keep = 0;
    #pragma unroll 1
    for (int r = 0; r < 24; ++r) {
      u64 kk = kmin(kmin(gk[0], gk[1]), kmin(gk[2], gk[3]));
      #pragma unroll
      for (int off = 32; off >= 1; off >>= 1) kk = kmin(__shfl_xor(kk, off), kk);
      const unsigned wm = (unsigned)kk;
      if (lane == r) keep = (int)wm;
      if (lane == (int)(wm & 63)) {
        const int j = (int)(wm >> 6);
        if (j < 16) {
          if (j < 8) { inv8(key,      j);      gk[0] = min8(key);      }
          else       { inv8(key + 8,  j - 8);  gk[1] = min8(key + 8);  }
        } else {
          if (j < 24){ inv8(key + 16, j - 16); gk[2] = min8(key + 16); }
          else       { inv8(key + 24, j - 24); gk[3] = min8(key + 24); }
        }
      }
    }
    if (lane < 24) idxout[(size_t)(b * 2048 + q) * 24 + lane] = keep;
  }
}

// ---- K3: champion — per-wave 2 points (48 rows), wave-private, (256,2) [spill OK] ----
__global__ __launch_bounds__(256, 2) void k_pre(
    const float* __restrict__ features, const int* __restrict__ idxin,
    const _Float16* __restrict__ wp, const float* __restrict__ alpha, const float* __restrict__ beta,
    const float* __restrict__ b1, const float* __restrict__ g1, const float* __restrict__ bb1,
    const float* __restrict__ b2, const float* __restrict__ g2, const float* __restrict__ bb2,
    _Float16* __restrict__ h0) {
  __shared__ _Float16 lds[4][48 * 128];
  const int wid = threadIdx.x >> 6, lane = threadIdx.x & 63;
  _Float16* L = lds[wid];
  const int wgl = blockIdx.x * 4 + wid;
  const int p0 = wgl * 2;
  const int b = p0 >> 11;
  const float* fb = features + (size_t)b * 2048 * 64;
  {
    const int c = lane;
    const float al = alpha[c], be = beta[c];
    #pragma unroll 1
    for (int pp = 0; pp < 2; ++pp) {
      const int p = p0 + pp;
      const int n = p & 2047;
      const int* ip = idxin + (size_t)p * 24;
      const float center = fb[n * 64 + c];
      float v[24]; float su = 0.f, sq = 0.f;
      #pragma unroll
      for (int k = 0; k < 24; ++k) {
        v[k] = fb[ip[k] * 64 + c];
        su += v[k]; sq = fmaf(v[k], v[k], sq);
      }
      const float mean = su * (1.f / 24.f);
      const float var = fmaxf((sq - 24.f * mean * mean) * (1.f / 23.f), 0.f);
      const float rs = 1.f / fmaxf(sqrtf(var), 1e-6f);
      const float c1 = rs * al;
      const float c0 = be - mean * c1 - center;
      const _Float16 ch = (_Float16)center;
      #pragma unroll
      for (int k = 0; k < 24; ++k) {
        const int row = pp * 24 + k;
        stH(L, row, c, ch);
        stH(L, row, 64 + c, (_Float16)fmaf(v[k], c1, c0));
      }
    }
  }
  __threadfence_block();
  const int g = lane >> 4, cr = lane & 15;
  half8 xres[3][4];
  #pragma unroll
  for (int mt = 0; mt < 3; ++mt)
    #pragma unroll
    for (int q = 0; q < 4; ++q)
      xres[mt][q] = ldA(L, mt * 16 + 4 * g + q, cr);
  res_block_dev<3, 0>(L, wp,         wp + 18432,
                      b1,       g1,       bb1,       b2,       g2,       bb2,       xres, lane, nullptr);
  res_block_dev<3, 1>(L, wp + 36864, wp + 55296,
                      b1 + 128, g1 + 128, bb1 + 128, b2 + 128, g2 + 128, bb2 + 128, xres, lane, nullptr);
  // max over the 24 rows of each point (rows 0..23 -> p0, 24..47 -> p0+1), all in f16
  half8 m0 = hmax8(hmax8(xres[0][0], xres[0][1]), hmax8(xres[0][2], xres[0][3]));
  m0 = hmax8(m0, shfl_h8(m0, 16));
  m0 = hmax8(m0, shfl_h8(m0, 32));
  half8 m1 = hmax8(hmax8(xres[1][0], xres[1][1]), hmax8(xres[1][2], xres[1][3]));
  m1 = hmax8(m1, shfl_h8(m1, 16));          // g0/g1 hold rows16..23 (p0); g2/g3 rows24..31 (p1)
  const half8 m1o = shfl_h8(m1, 32);        // bring p1-part to g0/g1 side
  half8 m2 = hmax8(hmax8(xres[2][0], xres[2][1]), hmax8(xres[2][2], xres[2][3]));
  m2 = hmax8(m2, shfl_h8(m2, 16));
  m2 = hmax8(m2, shfl_h8(m2, 32));
  if (g == 0) *(half8*)(h0 + (size_t)p0 * 128 + cr * 8)       = hmax8(m0, m1);
  if (g == 1) *(half8*)(h0 + (size_t)(p0 + 1) * 128 + cr * 8) = hmax8(m2, m1o);
}

// ---- K4: pos stage, per-wave 32 rows of h0 -> 2 res_blocks -> h1 (f32) ----
__global__ __launch_bounds__(128, 2) void k_pos(
    const _Float16* __restrict__ h0, const _Float16* __restrict__ wp,
    const float* __restrict__ b1, const float* __restrict__ g1, const float* __restrict__ bb1,
    const float* __restrict__ b2, const float* __restrict__ g2, const float* __restrict__ bb2,
    float* __restrict__ h1) {
  __shared__ _Float16 lds[2][32 * 128];
  const int wid = threadIdx.x >> 6, lane = threadIdx.x & 63;
  _Float16* L = lds[wid];
  const int wgl = blockIdx.x * 2 + wid;
  const size_t rowbase = (size_t)wgl * 32;
  #pragma unroll
  for (int i = 0; i < 8; ++i) {
    const int r = i * 4 + (lane >> 4), ch = lane & 15;
    const half8 tv = *(const half8*)(h0 + (rowbase + r) * 128 + ch * 8);
    stA(L, r, ch, tv);
  }
  __threadfence_block();
  const int g = lane >> 4, cr = lane & 15;
  half8 xres[2][4];
  #pragma unroll
  for (int mt = 0; mt < 2; ++mt)
    #pragma unroll
    for (int q = 0; q < 4; ++q)
      xres[mt][q] = ldA(L, mt * 16 + 4 * g + q, cr);
  res_block_dev<2, 0>(L, wp + 73728,  wp + 92160,  b1,       g1,       bb1,       b2,       g2,       bb2,       xres, lane, nullptr);
  res_block_dev<2, 2>(L, wp + 110592, wp + 129024, b1 + 128, g1 + 128, bb1 + 128, b2 + 128, g2 + 128, bb2 + 128, xres, lane, h1 + rowbase * 128);
}

// ---- K5: gather new_features (h1 by fps_idx, float4) + new_xyz ----
__global__ __launch_bounds__(256) void k_gather(const float* __restrict__ h1, const float* __restrict__ xyz,
                                                const int* __restrict__ fps, float* __restrict__ out) {
  const int i = blockIdx.x * 256 + threadIdx.x;
  const int FEAT4 = 8 * 1024 * 32;
  if (i < FEAT4) {
    const int c4 = i & 31, m = (i >> 5) & 1023, b = i >> 15;
    const int n = fps[b * 1024 + m];
    const f32x4 v = *(const f32x4*)(h1 + ((size_t)(b * 2048 + n)) * 128 + c4 * 4);
    *(f32x4*)(out + (size_t)i * 4) = v;
  } else {
    const int jj = i - FEAT4;
    if (jj < 8 * 1024 * 3) {
      const int dd = jj % 3, m = (jj / 3) & 1023, b = jj / 3072;
      const int n = fps[b * 1024 + m];
      out[8 * 1024 * 128 + jj] = xyz[((size_t)(b * 2048 + n)) * 3 + dd];
    }
  }
}

extern "C" void kernel_launch(void* const* d_in, const int* in_sizes, int n_in,
                              void* d_out, int out_size, void* d_ws, size_t ws_size,
                              hipStream_t stream) {
  const float* features = (const float*)d_in[0];
  const float* xyz      = (const float*)d_in[1];
  const int*   fps      = (const int*)d_in[2];
  const float* alpha    = (const float*)d_in[3];
  const float* beta     = (const float*)d_in[4];
  const float* pre_w1   = (const float*)d_in[5];
  const float* pre_b1   = (const float*)d_in[6];
  const float* pre_g1   = (const float*)d_in[7];
  const float* pre_bb1  = (const float*)d_in[8];
  const float* pre_w2   = (const float*)d_in[9];
  const float* pre_b2   = (const float*)d_in[10];
  const float* pre_g2   = (const float*)d_in[11];
  const float* pre_bb2  = (const float*)d_in[12];
  const float* pos_w1   = (const float*)d_in[13];
  const float* pos_b1   = (const float*)d_in[14];
  const float* pos_g1   = (const float*)d_in[15];
  const float* pos_bb1  = (const float*)d_in[16];
  const float* pos_w2   = (const float*)d_in[17];
  const float* pos_b2   = (const float*)d_in[18];
  const float* pos_g2   = (const float*)d_in[19];
  const float* pos_bb2  = (const float*)d_in[20];
  (void)in_sizes; (void)n_in; (void)out_size; (void)ws_size;

  char* ws = (char*)d_ws;                     // needs ~14.3 MB
  _Float16* wp   = (_Float16*)(ws);           // [0, 294912)
  int*      idxb = (int*)(ws + 524288);       // [512K, 2M)
  _Float16* h0   = (_Float16*)(ws + 2097152); // [2M, 6M)
  float*    h1   = (float*)(ws + 6291456);    // [6M, 14M)

  k_pack<<<dim3(576), dim3(256), 0, stream>>>(pre_w1, pre_w2, pos_w1, pos_w2, wp);
  k_knn<<<dim3(4096), dim3(256), 0, stream>>>(xyz, idxb);
  k_pre<<<dim3(2048), dim3(256), 0, stream>>>(features, idxb, wp, alpha, beta,
      pre_b1, pre_g1, pre_bb1, pre_b2, pre_g2, pre_bb2, h0);
  k_pos<<<dim3(256), dim3(128), 0, stream>>>(h0, wp,
      pos_b1, pos_g1, pos_bb1, pos_b2, pos_g2, pos_bb2, h1);
  k_gather<<<dim3(1120), dim3(256), 0, stream>>>(h1, xyz, fps, (float*)d_out);
}